// Round 15
// baseline (290.857 us; speedup 1.0000x reference)
//
#include <hip/hip_runtime.h>
#include <hip/hip_bf16.h>
#include <math.h>

#define Hh 32
#define Nseq 8192
#define Dh 128
#define NBd 32          // number of 256-row chunks / key blocks
#define BLKSZ 256
#define SAMP 256
#define CHK 64          // kv inner chunk
#define NCH 8
#define LOG32 3.4657359027997265f
#define SCALE 0.088388347648318447f
#define SKW 136         // s_k row width: 128 d + 8 pad (272B rows, 16B-aligned)
#define SVW 72          // s_vt row width: 64 keys + 8 pad (144B rows, 16B-aligned)
#define ORS 132         // epilogue LDS row stride in f32 (128 + 4 pad)

typedef float f32x4 __attribute__((ext_vector_type(4)));
typedef unsigned ui32x4 __attribute__((ext_vector_type(4)));
typedef __bf16 bf16x8 __attribute__((ext_vector_type(8)));

__device__ __forceinline__ f32x4 mfma16(bf16x8 a, bf16x8 b, f32x4 c) {
  return __builtin_amdgcn_mfma_f32_16x16x32_bf16(a, b, c, 0, 0, 0);
}

__device__ __forceinline__ bf16x8 cvt8(const float* __restrict__ p) {
  float4 a = ((const float4*)p)[0];
  float4 b = ((const float4*)p)[1];
  bf16x8 r;
  r[0] = (__bf16)a.x; r[1] = (__bf16)a.y; r[2] = (__bf16)a.z; r[3] = (__bf16)a.w;
  r[4] = (__bf16)b.x; r[5] = (__bf16)b.y; r[6] = (__bf16)b.z; r[7] = (__bf16)b.w;
  return r;
}

__device__ __forceinline__ bf16x8 cvt8v(float4 a, float4 b) {
  bf16x8 r;
  r[0] = (__bf16)a.x; r[1] = (__bf16)a.y; r[2] = (__bf16)a.z; r[3] = (__bf16)a.w;
  r[4] = (__bf16)b.x; r[5] = (__bf16)b.y; r[6] = (__bf16)b.z; r[7] = (__bf16)b.w;
  return r;
}

__device__ __forceinline__ unsigned pack2(float a, float b, float& ra, float& rb) {
  __bf16 ba = (__bf16)a, bb = (__bf16)b;
  ra = (float)ba; rb = (float)bb;
  return ((unsigned)__builtin_bit_cast(unsigned short, bb) << 16) |
         (unsigned)__builtin_bit_cast(unsigned short, ba);
}

// ---------------- LSH hash: one thread per row, sequential fp64 ----------------
__global__ __launch_bounds__(256) void lsh_hash_kernel(
    const float* __restrict__ q, const float* __restrict__ k,
    const float* __restrict__ proj, int* __restrict__ buckets) {
  int row = blockIdx.x * 256 + threadIdx.x;
  const float* x = ((row >> 18) ? k : q) + (size_t)(row & (Hh * Nseq - 1)) * Dh;
  double acc[7] = {0, 0, 0, 0, 0, 0, 0};
#pragma unroll 8
  for (int d0 = 0; d0 < Dh; d0 += 4) {
    float4 xv = *(const float4*)(x + d0);
    double x0 = (double)xv.x, x1 = (double)xv.y, x2 = (double)xv.z, x3 = (double)xv.w;
#pragma unroll
    for (int j = 0; j < 7; j++) {
      acc[j] = fma(x0, (double)proj[(d0 + 0) * 7 + j], acc[j]);
      acc[j] = fma(x1, (double)proj[(d0 + 1) * 7 + j], acc[j]);
      acc[j] = fma(x2, (double)proj[(d0 + 2) * 7 + j], acc[j]);
      acc[j] = fma(x3, (double)proj[(d0 + 3) * 7 + j], acc[j]);
    }
  }
  int bin = 0;
#pragma unroll
  for (int j = 0; j < 7; j++) bin |= (acc[j] > 0.0 ? 1 : 0) << j;
  buckets[row] = bin ^ (bin >> 1);
}

// ---------------- stable counting sort, 256 threads per (tensor, head) ----------
// thread t owns contiguous chunk [t*32, t*32+32) -> stable. ushort hist:
// max position 8191 < 65536.
__global__ __launch_bounds__(256) void bucket_sort_kernel(
    const int* __restrict__ buckets, int* __restrict__ idx) {
  __shared__ unsigned short hist[256][128];   // [chunk][bucket]
  __shared__ unsigned btot[128];
  __shared__ unsigned wsum[2];
  const int t = threadIdx.x;
  const int base = blockIdx.x * Nseq;

  {
    uint4* h4 = (uint4*)&hist[0][0];
#pragma unroll
    for (int j = 0; j < 16; j++) h4[t + j * 256] = uint4{0, 0, 0, 0};
  }
  __syncthreads();

  int bloc[32];
#pragma unroll 8
  for (int i = 0; i < 32; i++) {
    int b = buckets[base + t * 32 + i];
    bloc[i] = b;
    hist[t][b]++;
  }
  __syncthreads();

  unsigned v = 0;
  if (t < 128) {
    unsigned run = 0;
    for (int cch = 0; cch < 256; cch++) {
      unsigned h = hist[cch][t];
      hist[cch][t] = (unsigned short)run;
      run += h;
    }
    btot[t] = run;
    v = run;
  }
  __syncthreads();

  unsigned sc = v;
  if (t < 128) {
#pragma unroll
    for (int s = 1; s < 64; s <<= 1) {
      unsigned u = __shfl_up(sc, s);
      if ((t & 63) >= s) sc += u;
    }
    if ((t & 63) == 63) wsum[t >> 6] = sc;
  }
  __syncthreads();
  if (t < 128) {
    unsigned excl = sc - v + ((t >> 6) ? wsum[0] : 0u);
    btot[t] = excl;
  }
  __syncthreads();
  if (t < 128) {
    unsigned short e = (unsigned short)btot[t];
    for (int cch = 0; cch < 256; cch++) hist[cch][t] += e;
  }
  __syncthreads();

#pragma unroll 8
  for (int i = 0; i < 32; i++) {
    int b = bloc[i];
    unsigned pos = hist[t][b]++;
    idx[base + pos] = t * 32 + i;
  }
}

// ---------------- permute sampled keys only (reused 32x per head) ----------------
__global__ __launch_bounds__(256) void permute_samp_kernel(
    const float* __restrict__ k, const float* __restrict__ v,
    const int* __restrict__ k_idx, const int* __restrict__ sampled,
    __bf16* __restrict__ K_sp, __bf16* __restrict__ V_sp) {
  __shared__ __attribute__((aligned(16))) __bf16 s_t[Dh][SVW];
  const int tile = blockIdx.x, bh = blockIdx.y;
  const int t = threadIdx.x;
  const int j = t >> 2, seg = (t & 3) * 32;
  const int dpos = tile * 64 + j;
  const int sp = sampled[bh * SAMP + dpos];
  const int orig = k_idx[bh * Nseq + sp];
  {
    const float4* kp = (const float4*)(k + ((size_t)bh * Nseq + orig) * Dh + seg);
    __bf16* dst = K_sp + ((size_t)bh * SAMP + dpos) * Dh + seg;
#pragma unroll
    for (int i = 0; i < 4; i++) *(bf16x8*)(dst + i * 8) = cvt8v(kp[2 * i], kp[2 * i + 1]);
  }
  {
    const float4* vp = (const float4*)(v + ((size_t)bh * Nseq + orig) * Dh + seg);
#pragma unroll
    for (int i = 0; i < 8; i++) {
      float4 a = vp[i];
      s_t[seg + i * 4 + 0][j] = (__bf16)a.x;
      s_t[seg + i * 4 + 1][j] = (__bf16)a.y;
      s_t[seg + i * 4 + 2][j] = (__bf16)a.z;
      s_t[seg + i * 4 + 3][j] = (__bf16)a.w;
    }
  }
  __syncthreads();
  {
    int d = t >> 1, half = (t & 1) * 32;
    __bf16* dst = V_sp + ((size_t)(bh * Dh + d)) * SAMP + tile * 64 + half;
    const __bf16* srcp = &s_t[d][half];
#pragma unroll
    for (int i = 0; i < 4; i++) *(ui32x4*)(dst + i * 8) = *(const ui32x4*)(srcp + i * 8);
  }
}

// ---------------- fused attention: R14 structure + coalesced epilogue ----------
__global__ __launch_bounds__(512, 2) void hyper_attn_kernel(
    const float* __restrict__ q, const float* __restrict__ k, const float* __restrict__ v,
    const __bf16* __restrict__ K_sp, const __bf16* __restrict__ V_sp,
    const int* __restrict__ sampled, const int* __restrict__ q_idx,
    const int* __restrict__ k_idx, float* __restrict__ out) {
  __shared__ int s_orig[BLKSZ];
  __shared__ __attribute__((aligned(16))) float s_add[SAMP];
  __shared__ __attribute__((aligned(16))) __bf16 s_k[2][CHK][SKW];
  __shared__ __attribute__((aligned(16))) __bf16 s_vt[2][Dh][SVW];

  const int c = blockIdx.x, bh = blockIdx.y;
  const int tid = threadIdx.x;
  const int w = tid >> 6, l = tid & 63;
  const int l4 = l >> 4, lm = l & 15;
  const int jk = tid >> 3, pk = tid & 7;        // K-staging: key jk, d-seg pk*16
  const int dv = tid >> 2, ks = (tid & 3) * 16; // contig V-staging: d-row dv, key-seg ks

  {
    int jj = tid;
    if (jj < BLKSZ) {
      s_orig[jj] = k_idx[bh * Nseq + c * BLKSZ + jj];
    } else {
      int sp = sampled[bh * SAMP + (jj - BLKSZ)];
      s_add[jj - BLKSZ] = ((sp >> 8) == c) ? -1e38f : LOG32;
    }
  }

  // Q fragments (MFMA B-operand: B[d][q=lane&15])
  bf16x8 qf[2][4];
  const int* qi = q_idx + bh * Nseq + c * BLKSZ + w * 32;
#pragma unroll
  for (int rt = 0; rt < 2; rt++) {
    int orig = qi[rt * 16 + lm];
    const float* qp = q + ((size_t)bh * Nseq + orig) * Dh + l4 * 8;
#pragma unroll
    for (int dc = 0; dc < 4; dc++) qf[rt][dc] = cvt8(qp + dc * 32);
  }

  f32x4 O[2][8];
  float mrow[2] = {-INFINITY, -INFINITY};
  float lsum[2] = {0.f, 0.f};
#pragma unroll
  for (int rt = 0; rt < 2; rt++)
#pragma unroll
    for (int dt = 0; dt < 8; dt++) { O[rt][dt][0]=0.f; O[rt][dt][1]=0.f; O[rt][dt][2]=0.f; O[rt][dt][3]=0.f; }

  __syncthreads();

  // prologue: stage chunk 0 (block keys, gather + cvt)
  {
    int origk = s_orig[jk];
    const float* kp = k + ((size_t)bh * Nseq + origk) * Dh + pk * 16;
    *(bf16x8*)&s_k[0][jk][pk * 16]     = cvt8(kp);
    *(bf16x8*)&s_k[0][jk][pk * 16 + 8] = cvt8(kp + 8);
    int origv = s_orig[l];
    const float* vp = v + ((size_t)bh * Nseq + origv) * Dh + w * 16;
    float4 A = ((const float4*)vp)[0], B = ((const float4*)vp)[1];
    float4 C = ((const float4*)vp)[2], Dv = ((const float4*)vp)[3];
    float tmp[16] = {A.x,A.y,A.z,A.w,B.x,B.y,B.z,B.w,C.x,C.y,C.z,C.w,Dv.x,Dv.y,Dv.z,Dv.w};
#pragma unroll
    for (int dd = 0; dd < 16; dd++) s_vt[0][w * 16 + dd][l] = (__bf16)tmp[dd];
  }
  __syncthreads();

  const int laneA = lm + 32 * (l4 & 1);
  const bool hi = (l4 >> 1) & 1;

  for (int ch = 0; ch < NCH; ch++) {
    const int cur = ch & 1;
    const int cn = ch + 1;
    const bool pfg = (cn < 4);               // next chunk is block keys (gather)
    const bool pfc = (cn >= 4 && cn < NCH);  // next chunk is sampled (contiguous)

    float4 kA, kB, kC, kD, vA, vB, vC, vD;
    ui32x4 ksA, ksB, vsA, vsB;
    if (pfg) {
      int origk = s_orig[cn * CHK + jk];
      const float4* kp = (const float4*)(k + ((size_t)bh * Nseq + origk) * Dh + pk * 16);
      kA = kp[0]; kB = kp[1]; kC = kp[2]; kD = kp[3];
      int origv = s_orig[cn * CHK + l];
      const float4* vp = (const float4*)(v + ((size_t)bh * Nseq + origv) * Dh + w * 16);
      vA = vp[0]; vB = vp[1]; vC = vp[2]; vD = vp[3];
    } else if (pfc) {
      const __bf16* kp = K_sp + ((size_t)(bh * SAMP + (cn - 4) * CHK + jk)) * Dh + pk * 16;
      ksA = *(const ui32x4*)kp; ksB = *(const ui32x4*)(kp + 8);
      const __bf16* vp = V_sp + ((size_t)(bh * Dh + dv)) * SAMP + (cn - 4) * CHK + ks;
      vsA = *(const ui32x4*)vp; vsB = *(const ui32x4*)(vp + 8);
    }

    // S^T = K·Q^T (+scale +addend)
    float sc[2][4][4];
#pragma unroll
    for (int ct = 0; ct < 4; ct++) {
      f32x4 acc0, acc1;
      acc0[0]=0.f;acc0[1]=0.f;acc0[2]=0.f;acc0[3]=0.f;
      acc1[0]=0.f;acc1[1]=0.f;acc1[2]=0.f;acc1[3]=0.f;
#pragma unroll
      for (int dc = 0; dc < 4; dc++) {
        bf16x8 kf = *(const bf16x8*)&s_k[cur][ct * 16 + lm][dc * 32 + l4 * 8];
        acc0 = mfma16(kf, qf[0][dc], acc0);
        acc1 = mfma16(kf, qf[1][dc], acc1);
      }
      f32x4 addv;
      if (ch < 4) { addv[0]=0.f; addv[1]=0.f; addv[2]=0.f; addv[3]=0.f; }
      else addv = *(const f32x4*)&s_add[(ch - 4) * CHK + ct * 16 + l4 * 4];
#pragma unroll
      for (int r = 0; r < 4; r++) {
        sc[0][ct][r] = acc0[r] * SCALE + addv[r];
        sc[1][ct][r] = acc1[r] * SCALE + addv[r];
      }
    }

    // online softmax per q-row
    unsigned q01[2][4], q23[2][4];
#pragma unroll
    for (int rt = 0; rt < 2; rt++) {
      float mc = sc[rt][0][0];
#pragma unroll
      for (int ct = 0; ct < 4; ct++)
#pragma unroll
        for (int r = 0; r < 4; r++) mc = fmaxf(mc, sc[rt][ct][r]);
      mc = fmaxf(mc, __shfl_xor(mc, 16));
      mc = fmaxf(mc, __shfl_xor(mc, 32));
      float mn = fmaxf(mrow[rt], mc);
      float alpha = __expf(mrow[rt] - mn);
      mrow[rt] = mn;
      f32x4 aO;
#pragma unroll
      for (int r = 0; r < 4; r++) aO[r] = __shfl(alpha, l4 * 4 + r);
#pragma unroll
      for (int dt = 0; dt < 8; dt++) O[rt][dt] *= aO;
      float rsum = 0.f;
#pragma unroll
      for (int ct = 0; ct < 4; ct++) {
        float p0 = __expf(sc[rt][ct][0] - mn);
        float p1 = __expf(sc[rt][ct][1] - mn);
        float p2 = __expf(sc[rt][ct][2] - mn);
        float p3 = __expf(sc[rt][ct][3] - mn);
        float ra, rb, rc, rd;
        q01[rt][ct] = pack2(p0, p1, ra, rb);
        q23[rt][ct] = pack2(p2, p3, rc, rd);
        rsum += (ra + rb) + (rc + rd);
      }
      rsum += __shfl_xor(rsum, 16);
      rsum += __shfl_xor(rsum, 32);
      lsum[rt] = lsum[rt] * alpha + rsum;
    }

    // write staged chunk cn into buffer cur^1
    if (pfg) {
      *(bf16x8*)&s_k[cur ^ 1][jk][pk * 16]     = cvt8v(kA, kB);
      *(bf16x8*)&s_k[cur ^ 1][jk][pk * 16 + 8] = cvt8v(kC, kD);
      float ta[16] = {vA.x,vA.y,vA.z,vA.w,vB.x,vB.y,vB.z,vB.w,
                      vC.x,vC.y,vC.z,vC.w,vD.x,vD.y,vD.z,vD.w};
#pragma unroll
      for (int dd = 0; dd < 16; dd++) s_vt[cur ^ 1][w * 16 + dd][l] = (__bf16)ta[dd];
    } else if (pfc) {
      *(ui32x4*)&s_k[cur ^ 1][jk][pk * 16]     = ksA;
      *(ui32x4*)&s_k[cur ^ 1][jk][pk * 16 + 8] = ksB;
      *(ui32x4*)&s_vt[cur ^ 1][dv][ks]     = vsA;
      *(ui32x4*)&s_vt[cur ^ 1][dv][ks + 8] = vsB;
    }

    // PV: build A-frag via packed shuffles, then MFMA
#pragma unroll
    for (int kc = 0; kc < 2; kc++) {
      bf16x8 pa[2];
#pragma unroll
      for (int rt = 0; rt < 2; rt++) {
        unsigned a0 = __shfl((int)q01[rt][2 * kc],     laneA);
        unsigned b0 = __shfl((int)q01[rt][2 * kc + 1], laneA);
        unsigned a1 = __shfl((int)q23[rt][2 * kc],     laneA);
        unsigned b1 = __shfl((int)q23[rt][2 * kc + 1], laneA);
        unsigned a2 = __shfl((int)q01[rt][2 * kc],     laneA + 16);
        unsigned b2 = __shfl((int)q01[rt][2 * kc + 1], laneA + 16);
        unsigned a3 = __shfl((int)q23[rt][2 * kc],     laneA + 16);
        unsigned b3 = __shfl((int)q23[rt][2 * kc + 1], laneA + 16);
        ui32x4 pw;
        pw[0] = hi ? b0 : a0;
        pw[1] = hi ? b1 : a1;
        pw[2] = hi ? b2 : a2;
        pw[3] = hi ? b3 : a3;
        pa[rt] = __builtin_bit_cast(bf16x8, pw);
      }
#pragma unroll
      for (int dt = 0; dt < 8; dt++) {
        bf16x8 vb = *(const bf16x8*)&s_vt[cur][dt * 16 + lm][kc * 32 + l4 * 8];
        O[0][dt] = mfma16(pa[0], vb, O[0][dt]);
        O[1][dt] = mfma16(pa[1], vb, O[1][dt]);
      }
    }
    __syncthreads();
  }

  // ---- epilogue: normalize in-reg, transpose via LDS, coalesced row stores ----
  float invr_[2][4];
#pragma unroll
  for (int rt = 0; rt < 2; rt++) {
    float inv = 1.0f / lsum[rt];
#pragma unroll
    for (int r = 0; r < 4; r++) invr_[rt][r] = __shfl(inv, l4 * 4 + r);
  }
  float* lds_o = (float*)s_vt;     // 8 waves x 8 rows x ORS f32 = 33.8KB <= 36.9KB
#pragma unroll
  for (int b = 0; b < 4; b++) {
    const int rt = b >> 1, pair = b & 1;      // active l4 groups {2*pair, 2*pair+1}
    __syncthreads();                          // prior batch fully read
    if ((l4 >> 1) == pair) {
      int rbase = (l4 & 1) * 4;
#pragma unroll
      for (int r = 0; r < 4; r++) {
        float* dst = lds_o + (w * 8 + rbase + r) * ORS + lm;
#pragma unroll
        for (int dt = 0; dt < 8; dt++) dst[dt * 16] = O[rt][dt][r] * invr_[rt][r];
      }
    }
    __syncthreads();
    {
      int rloc = l >> 3, seg = (l & 7) * 16;
      int g = w * 32 + rt * 16 + pair * 8 + rloc;
      int orow = q_idx[bh * Nseq + c * BLKSZ + g];
      const float* src = lds_o + (w * 8 + rloc) * ORS + seg;
      float* op = out + ((size_t)bh * Nseq + orow) * Dh + seg;
#pragma unroll
      for (int i = 0; i < 4; i++)
        *(f32x4*)(op + i * 4) = *(const f32x4*)(src + i * 4);
    }
  }
}

extern "C" void kernel_launch(void* const* d_in, const int* in_sizes, int n_in,
                              void* d_out, int out_size, void* d_ws, size_t ws_size,
                              hipStream_t stream) {
  const float* q    = (const float*)d_in[0];
  const float* k    = (const float*)d_in[1];
  const float* v    = (const float*)d_in[2];
  const float* proj = (const float*)d_in[3];
  const int* samp   = (const int*)d_in[4];
  float* out = (float*)d_out;

  int* buckets = (int*)d_ws;                       // 2MB
  int* idx = buckets + 2 * Hh * Nseq;              // 2MB (q_idx, k_idx)
  __bf16* K_sp = (__bf16*)(idx + 2 * Hh * Nseq);   // 2MB [Hh][SAMP][Dh]
  __bf16* V_sp = K_sp + (size_t)Hh * SAMP * Dh;    // 2MB [Hh][Dh][SAMP]

  lsh_hash_kernel<<<(2 * Hh * Nseq) / 256, 256, 0, stream>>>(q, k, proj, buckets);
  bucket_sort_kernel<<<2 * Hh, 256, 0, stream>>>(buckets, idx);
  permute_samp_kernel<<<dim3(4, Hh), 256, 0, stream>>>(
      k, v, idx + Hh * Nseq /*k_idx*/, samp, K_sp, V_sp);
  hyper_attn_kernel<<<dim3(NBd, Hh), 512, 0, stream>>>(
      q, k, v, K_sp, V_sp, samp, idx /*q_idx*/, idx + Hh * Nseq /*k_idx*/, out);
}

// Round 16
// 266.255 us; speedup vs baseline: 1.0924x; 1.0924x over previous
//
#include <hip/hip_runtime.h>
#include <hip/hip_bf16.h>
#include <math.h>

#define Hh 32
#define Nseq 8192
#define Dh 128
#define NBd 32          // number of 256-row chunks / key blocks
#define BLKSZ 256
#define SAMP 256
#define CHK 64          // kv inner chunk
#define NCH 8
#define LOG32 3.4657359027997265f
#define SCALE 0.088388347648318447f
#define SKW 136         // s_k row width: 128 d + 8 pad (272B rows, 16B-aligned)
#define SVW 72          // s_vt row width: 64 keys + 8 pad (144B rows, 16B-aligned)

typedef float f32x4 __attribute__((ext_vector_type(4)));
typedef unsigned ui32x4 __attribute__((ext_vector_type(4)));
typedef __bf16 bf16x8 __attribute__((ext_vector_type(8)));

__device__ __forceinline__ f32x4 mfma16(bf16x8 a, bf16x8 b, f32x4 c) {
  return __builtin_amdgcn_mfma_f32_16x16x32_bf16(a, b, c, 0, 0, 0);
}

__device__ __forceinline__ bf16x8 cvt8(const float* __restrict__ p) {
  float4 a = ((const float4*)p)[0];
  float4 b = ((const float4*)p)[1];
  bf16x8 r;
  r[0] = (__bf16)a.x; r[1] = (__bf16)a.y; r[2] = (__bf16)a.z; r[3] = (__bf16)a.w;
  r[4] = (__bf16)b.x; r[5] = (__bf16)b.y; r[6] = (__bf16)b.z; r[7] = (__bf16)b.w;
  return r;
}

__device__ __forceinline__ bf16x8 cvt8v(float4 a, float4 b) {
  bf16x8 r;
  r[0] = (__bf16)a.x; r[1] = (__bf16)a.y; r[2] = (__bf16)a.z; r[3] = (__bf16)a.w;
  r[4] = (__bf16)b.x; r[5] = (__bf16)b.y; r[6] = (__bf16)b.z; r[7] = (__bf16)b.w;
  return r;
}

__device__ __forceinline__ unsigned pack2(float a, float b, float& ra, float& rb) {
  __bf16 ba = (__bf16)a, bb = (__bf16)b;
  ra = (float)ba; rb = (float)bb;
  return ((unsigned)__builtin_bit_cast(unsigned short, bb) << 16) |
         (unsigned)__builtin_bit_cast(unsigned short, ba);
}

// ---------------- LSH hash: one thread per row, sequential fp64 ----------------
__global__ __launch_bounds__(256) void lsh_hash_kernel(
    const float* __restrict__ q, const float* __restrict__ k,
    const float* __restrict__ proj, int* __restrict__ buckets) {
  int row = blockIdx.x * 256 + threadIdx.x;
  const float* x = ((row >> 18) ? k : q) + (size_t)(row & (Hh * Nseq - 1)) * Dh;
  double acc[7] = {0, 0, 0, 0, 0, 0, 0};
#pragma unroll 8
  for (int d0 = 0; d0 < Dh; d0 += 4) {
    float4 xv = *(const float4*)(x + d0);
    double x0 = (double)xv.x, x1 = (double)xv.y, x2 = (double)xv.z, x3 = (double)xv.w;
#pragma unroll
    for (int j = 0; j < 7; j++) {
      acc[j] = fma(x0, (double)proj[(d0 + 0) * 7 + j], acc[j]);
      acc[j] = fma(x1, (double)proj[(d0 + 1) * 7 + j], acc[j]);
      acc[j] = fma(x2, (double)proj[(d0 + 2) * 7 + j], acc[j]);
      acc[j] = fma(x3, (double)proj[(d0 + 3) * 7 + j], acc[j]);
    }
  }
  int bin = 0;
#pragma unroll
  for (int j = 0; j < 7; j++) bin |= (acc[j] > 0.0 ? 1 : 0) << j;
  buckets[row] = bin ^ (bin >> 1);
}

// ---------------- stable counting sort, 256 threads per (tensor, head) ----------
// (R15 version: measured fast, correct)
__global__ __launch_bounds__(256) void bucket_sort_kernel(
    const int* __restrict__ buckets, int* __restrict__ idx) {
  __shared__ unsigned short hist[256][128];   // [chunk][bucket]
  __shared__ unsigned btot[128];
  __shared__ unsigned wsum[2];
  const int t = threadIdx.x;
  const int base = blockIdx.x * Nseq;

  {
    uint4* h4 = (uint4*)&hist[0][0];
#pragma unroll
    for (int j = 0; j < 16; j++) h4[t + j * 256] = uint4{0, 0, 0, 0};
  }
  __syncthreads();

  int bloc[32];
#pragma unroll 8
  for (int i = 0; i < 32; i++) {
    int b = buckets[base + t * 32 + i];
    bloc[i] = b;
    hist[t][b]++;
  }
  __syncthreads();

  unsigned v = 0;
  if (t < 128) {
    unsigned run = 0;
    for (int cch = 0; cch < 256; cch++) {
      unsigned h = hist[cch][t];
      hist[cch][t] = (unsigned short)run;
      run += h;
    }
    btot[t] = run;
    v = run;
  }
  __syncthreads();

  unsigned sc = v;
  if (t < 128) {
#pragma unroll
    for (int s = 1; s < 64; s <<= 1) {
      unsigned u = __shfl_up(sc, s);
      if ((t & 63) >= s) sc += u;
    }
    if ((t & 63) == 63) wsum[t >> 6] = sc;
  }
  __syncthreads();
  if (t < 128) {
    unsigned excl = sc - v + ((t >> 6) ? wsum[0] : 0u);
    btot[t] = excl;
  }
  __syncthreads();
  if (t < 128) {
    unsigned short e = (unsigned short)btot[t];
    for (int cch = 0; cch < 256; cch++) hist[cch][t] += e;
  }
  __syncthreads();

#pragma unroll 8
  for (int i = 0; i < 32; i++) {
    int b = bloc[i];
    unsigned pos = hist[t][b]++;
    idx[base + pos] = t * 32 + i;
  }
}

// ---------------- permute sampled keys only (reused 32x per head) ----------------
__global__ __launch_bounds__(256) void permute_samp_kernel(
    const float* __restrict__ k, const float* __restrict__ v,
    const int* __restrict__ k_idx, const int* __restrict__ sampled,
    __bf16* __restrict__ K_sp, __bf16* __restrict__ V_sp) {
  __shared__ __attribute__((aligned(16))) __bf16 s_t[Dh][SVW];
  const int tile = blockIdx.x, bh = blockIdx.y;
  const int t = threadIdx.x;
  const int j = t >> 2, seg = (t & 3) * 32;
  const int dpos = tile * 64 + j;
  const int sp = sampled[bh * SAMP + dpos];
  const int orig = k_idx[bh * Nseq + sp];
  {
    const float4* kp = (const float4*)(k + ((size_t)bh * Nseq + orig) * Dh + seg);
    __bf16* dst = K_sp + ((size_t)bh * SAMP + dpos) * Dh + seg;
#pragma unroll
    for (int i = 0; i < 4; i++) *(bf16x8*)(dst + i * 8) = cvt8v(kp[2 * i], kp[2 * i + 1]);
  }
  {
    const float4* vp = (const float4*)(v + ((size_t)bh * Nseq + orig) * Dh + seg);
#pragma unroll
    for (int i = 0; i < 8; i++) {
      float4 a = vp[i];
      s_t[seg + i * 4 + 0][j] = (__bf16)a.x;
      s_t[seg + i * 4 + 1][j] = (__bf16)a.y;
      s_t[seg + i * 4 + 2][j] = (__bf16)a.z;
      s_t[seg + i * 4 + 3][j] = (__bf16)a.w;
    }
  }
  __syncthreads();
  {
    int d = t >> 1, half = (t & 1) * 32;
    __bf16* dst = V_sp + ((size_t)(bh * Dh + d)) * SAMP + tile * 64 + half;
    const __bf16* srcp = &s_t[d][half];
#pragma unroll
    for (int i = 0; i < 4; i++) *(ui32x4*)(dst + i * 8) = *(const ui32x4*)(srcp + i * 8);
  }
}

// ---------------- fused attention: R14 version verbatim (best measured: 189us) ----
__global__ __launch_bounds__(512, 2) void hyper_attn_kernel(
    const float* __restrict__ q, const float* __restrict__ k, const float* __restrict__ v,
    const __bf16* __restrict__ K_sp, const __bf16* __restrict__ V_sp,
    const int* __restrict__ sampled, const int* __restrict__ q_idx,
    const int* __restrict__ k_idx, float* __restrict__ out) {
  __shared__ int s_orig[BLKSZ];
  __shared__ __attribute__((aligned(16))) float s_add[SAMP];
  __shared__ __attribute__((aligned(16))) __bf16 s_k[2][CHK][SKW];
  __shared__ __attribute__((aligned(16))) __bf16 s_vt[2][Dh][SVW];

  const int c = blockIdx.x, bh = blockIdx.y;
  const int tid = threadIdx.x;
  const int w = tid >> 6, l = tid & 63;
  const int l4 = l >> 4, lm = l & 15;
  const int jk = tid >> 3, pk = tid & 7;        // K-staging: key jk, d-seg pk*16
  const int dv = tid >> 2, ks = (tid & 3) * 16; // contig V-staging: d-row dv, key-seg ks

  {
    int jj = tid;
    if (jj < BLKSZ) {
      s_orig[jj] = k_idx[bh * Nseq + c * BLKSZ + jj];
    } else {
      int sp = sampled[bh * SAMP + (jj - BLKSZ)];
      s_add[jj - BLKSZ] = ((sp >> 8) == c) ? -1e38f : LOG32;
    }
  }

  // Q fragments (MFMA B-operand: B[d][q=lane&15])
  bf16x8 qf[2][4];
  const int* qi = q_idx + bh * Nseq + c * BLKSZ + w * 32;
#pragma unroll
  for (int rt = 0; rt < 2; rt++) {
    int orig = qi[rt * 16 + lm];
    const float* qp = q + ((size_t)bh * Nseq + orig) * Dh + l4 * 8;
#pragma unroll
    for (int dc = 0; dc < 4; dc++) qf[rt][dc] = cvt8(qp + dc * 32);
  }

  f32x4 O[2][8];
  float mrow[2] = {-INFINITY, -INFINITY};
  float lsum[2] = {0.f, 0.f};
#pragma unroll
  for (int rt = 0; rt < 2; rt++)
#pragma unroll
    for (int dt = 0; dt < 8; dt++) { O[rt][dt][0]=0.f; O[rt][dt][1]=0.f; O[rt][dt][2]=0.f; O[rt][dt][3]=0.f; }

  __syncthreads();

  // prologue: stage chunk 0 (block keys, gather + cvt)
  {
    int origk = s_orig[jk];
    const float* kp = k + ((size_t)bh * Nseq + origk) * Dh + pk * 16;
    *(bf16x8*)&s_k[0][jk][pk * 16]     = cvt8(kp);
    *(bf16x8*)&s_k[0][jk][pk * 16 + 8] = cvt8(kp + 8);
    int origv = s_orig[l];
    const float* vp = v + ((size_t)bh * Nseq + origv) * Dh + w * 16;
    float4 A = ((const float4*)vp)[0], B = ((const float4*)vp)[1];
    float4 C = ((const float4*)vp)[2], Dv = ((const float4*)vp)[3];
    float tmp[16] = {A.x,A.y,A.z,A.w,B.x,B.y,B.z,B.w,C.x,C.y,C.z,C.w,Dv.x,Dv.y,Dv.z,Dv.w};
#pragma unroll
    for (int dd = 0; dd < 16; dd++) s_vt[0][w * 16 + dd][l] = (__bf16)tmp[dd];
  }
  __syncthreads();

  const int laneA = lm + 32 * (l4 & 1);
  const bool hi = (l4 >> 1) & 1;

  for (int ch = 0; ch < NCH; ch++) {
    const int cur = ch & 1;
    const int cn = ch + 1;
    const bool pfg = (cn < 4);               // next chunk is block keys (gather)
    const bool pfc = (cn >= 4 && cn < NCH);  // next chunk is sampled (contiguous)

    // issue next-chunk loads (latency hides under QK+softmax)
    float4 kA, kB, kC, kD, vA, vB, vC, vD;
    ui32x4 ksA, ksB, vsA, vsB;
    if (pfg) {
      int origk = s_orig[cn * CHK + jk];
      const float4* kp = (const float4*)(k + ((size_t)bh * Nseq + origk) * Dh + pk * 16);
      kA = kp[0]; kB = kp[1]; kC = kp[2]; kD = kp[3];
      int origv = s_orig[cn * CHK + l];
      const float4* vp = (const float4*)(v + ((size_t)bh * Nseq + origv) * Dh + w * 16);
      vA = vp[0]; vB = vp[1]; vC = vp[2]; vD = vp[3];
    } else if (pfc) {
      const __bf16* kp = K_sp + ((size_t)(bh * SAMP + (cn - 4) * CHK + jk)) * Dh + pk * 16;
      ksA = *(const ui32x4*)kp; ksB = *(const ui32x4*)(kp + 8);
      const __bf16* vp = V_sp + ((size_t)(bh * Dh + dv)) * SAMP + (cn - 4) * CHK + ks;
      vsA = *(const ui32x4*)vp; vsB = *(const ui32x4*)(vp + 8);
    }

    // S^T = K·Q^T (+scale +addend): lane holds key = ch*64+ct*16+l4*4+r, q = lm
    float sc[2][4][4];
#pragma unroll
    for (int ct = 0; ct < 4; ct++) {
      f32x4 acc0, acc1;
      acc0[0]=0.f;acc0[1]=0.f;acc0[2]=0.f;acc0[3]=0.f;
      acc1[0]=0.f;acc1[1]=0.f;acc1[2]=0.f;acc1[3]=0.f;
#pragma unroll
      for (int dc = 0; dc < 4; dc++) {
        bf16x8 kf = *(const bf16x8*)&s_k[cur][ct * 16 + lm][dc * 32 + l4 * 8];
        acc0 = mfma16(kf, qf[0][dc], acc0);
        acc1 = mfma16(kf, qf[1][dc], acc1);
      }
      f32x4 addv;
      if (ch < 4) { addv[0]=0.f; addv[1]=0.f; addv[2]=0.f; addv[3]=0.f; }
      else addv = *(const f32x4*)&s_add[(ch - 4) * CHK + ct * 16 + l4 * 4];
#pragma unroll
      for (int r = 0; r < 4; r++) {
        sc[0][ct][r] = acc0[r] * SCALE + addv[r];
        sc[1][ct][r] = acc1[r] * SCALE + addv[r];
      }
    }

    // online softmax per q-row (= lane lm, replicated across l4 groups)
    unsigned q01[2][4], q23[2][4];
#pragma unroll
    for (int rt = 0; rt < 2; rt++) {
      float mc = sc[rt][0][0];
#pragma unroll
      for (int ct = 0; ct < 4; ct++)
#pragma unroll
        for (int r = 0; r < 4; r++) mc = fmaxf(mc, sc[rt][ct][r]);
      mc = fmaxf(mc, __shfl_xor(mc, 16));
      mc = fmaxf(mc, __shfl_xor(mc, 32));
      float mn = fmaxf(mrow[rt], mc);
      float alpha = __expf(mrow[rt] - mn);
      mrow[rt] = mn;
      f32x4 aO;
#pragma unroll
      for (int r = 0; r < 4; r++) aO[r] = __shfl(alpha, l4 * 4 + r);
#pragma unroll
      for (int dt = 0; dt < 8; dt++) O[rt][dt] *= aO;
      float rsum = 0.f;
#pragma unroll
      for (int ct = 0; ct < 4; ct++) {
        float p0 = __expf(sc[rt][ct][0] - mn);
        float p1 = __expf(sc[rt][ct][1] - mn);
        float p2 = __expf(sc[rt][ct][2] - mn);
        float p3 = __expf(sc[rt][ct][3] - mn);
        float ra, rb, rc, rd;
        q01[rt][ct] = pack2(p0, p1, ra, rb);
        q23[rt][ct] = pack2(p2, p3, rc, rd);
        rsum += (ra + rb) + (rc + rd);
      }
      rsum += __shfl_xor(rsum, 16);
      rsum += __shfl_xor(rsum, 32);
      lsum[rt] = lsum[rt] * alpha + rsum;
    }

    // write staged chunk cn into buffer cur^1
    if (pfg) {
      *(bf16x8*)&s_k[cur ^ 1][jk][pk * 16]     = cvt8v(kA, kB);
      *(bf16x8*)&s_k[cur ^ 1][jk][pk * 16 + 8] = cvt8v(kC, kD);
      float ta[16] = {vA.x,vA.y,vA.z,vA.w,vB.x,vB.y,vB.z,vB.w,
                      vC.x,vC.y,vC.z,vC.w,vD.x,vD.y,vD.z,vD.w};
#pragma unroll
      for (int dd = 0; dd < 16; dd++) s_vt[cur ^ 1][w * 16 + dd][l] = (__bf16)ta[dd];
    } else if (pfc) {
      *(ui32x4*)&s_k[cur ^ 1][jk][pk * 16]     = ksA;
      *(ui32x4*)&s_k[cur ^ 1][jk][pk * 16 + 8] = ksB;
      *(ui32x4*)&s_vt[cur ^ 1][dv][ks]     = vsA;
      *(ui32x4*)&s_vt[cur ^ 1][dv][ks + 8] = vsB;
    }

    // PV: build A-frag P[q=lm][kc*32+l4*8+j] via packed shuffles, then MFMA
#pragma unroll
    for (int kc = 0; kc < 2; kc++) {
      bf16x8 pa[2];
#pragma unroll
      for (int rt = 0; rt < 2; rt++) {
        unsigned a0 = __shfl((int)q01[rt][2 * kc],     laneA);
        unsigned b0 = __shfl((int)q01[rt][2 * kc + 1], laneA);
        unsigned a1 = __shfl((int)q23[rt][2 * kc],     laneA);
        unsigned b1 = __shfl((int)q23[rt][2 * kc + 1], laneA);
        unsigned a2 = __shfl((int)q01[rt][2 * kc],     laneA + 16);
        unsigned b2 = __shfl((int)q01[rt][2 * kc + 1], laneA + 16);
        unsigned a3 = __shfl((int)q23[rt][2 * kc],     laneA + 16);
        unsigned b3 = __shfl((int)q23[rt][2 * kc + 1], laneA + 16);
        ui32x4 pw;
        pw[0] = hi ? b0 : a0;
        pw[1] = hi ? b1 : a1;
        pw[2] = hi ? b2 : a2;
        pw[3] = hi ? b3 : a3;
        pa[rt] = __builtin_bit_cast(bf16x8, pw);
      }
#pragma unroll
      for (int dt = 0; dt < 8; dt++) {
        bf16x8 vb = *(const bf16x8*)&s_vt[cur][dt * 16 + lm][kc * 32 + l4 * 8];
        O[0][dt] = mfma16(pa[0], vb, O[0][dt]);
        O[1][dt] = mfma16(pa[1], vb, O[1][dt]);
      }
    }
    __syncthreads();
  }

  // epilogue: normalize and scatter to original row order
#pragma unroll
  for (int rt = 0; rt < 2; rt++) {
    float inv = 1.0f / lsum[rt];
    f32x4 invr;
#pragma unroll
    for (int r = 0; r < 4; r++) invr[r] = __shfl(inv, l4 * 4 + r);
#pragma unroll
    for (int r = 0; r < 4; r++) {
      int orow = q_idx[bh * Nseq + c * BLKSZ + w * 32 + rt * 16 + l4 * 4 + r];
      float* op = out + ((size_t)bh * Nseq + orow) * Dh + lm;
#pragma unroll
      for (int dt = 0; dt < 8; dt++) op[dt * 16] = O[rt][dt][r] * invr[r];
    }
  }
}

extern "C" void kernel_launch(void* const* d_in, const int* in_sizes, int n_in,
                              void* d_out, int out_size, void* d_ws, size_t ws_size,
                              hipStream_t stream) {
  const float* q    = (const float*)d_in[0];
  const float* k    = (const float*)d_in[1];
  const float* v    = (const float*)d_in[2];
  const float* proj = (const float*)d_in[3];
  const int* samp   = (const int*)d_in[4];
  float* out = (float*)d_out;

  int* buckets = (int*)d_ws;                       // 2MB
  int* idx = buckets + 2 * Hh * Nseq;              // 2MB (q_idx, k_idx)
  __bf16* K_sp = (__bf16*)(idx + 2 * Hh * Nseq);   // 2MB [Hh][SAMP][Dh]
  __bf16* V_sp = K_sp + (size_t)Hh * SAMP * Dh;    // 2MB [Hh][Dh][SAMP]

  lsh_hash_kernel<<<(2 * Hh * Nseq) / 256, 256, 0, stream>>>(q, k, proj, buckets);
  bucket_sort_kernel<<<2 * Hh, 256, 0, stream>>>(buckets, idx);
  permute_samp_kernel<<<dim3(4, Hh), 256, 0, stream>>>(
      k, v, idx + Hh * Nseq /*k_idx*/, samp, K_sp, V_sp);
  hyper_attn_kernel<<<dim3(NBd, Hh), 512, 0, stream>>>(
      q, k, v, K_sp, V_sp, samp, idx /*q_idx*/, idx + Hh * Nseq /*k_idx*/, out);
}